// Round 8
// baseline (162.270 us; speedup 1.0000x reference)
//
#include <hip/hip_runtime.h>
#include <math.h>

#define FMPX 40
#define NPOS 1600          // 40*40
#define NCLS 80
#define NBOX 8000
#define KDIM 512
#define CAP  256           // per-class candidate capacity (expected ~100-130/class)

// anchor (w,h) pairs
__constant__ float c_aw[5] = {17.f, 55.f, 92.f, 202.f, 289.f};
__constant__ float c_ah[5] = {25.f, 75.f, 206.f, 21.f, 311.f};

__device__ __forceinline__ float sigf(float x) { return 1.0f / (1.0f + expf(-x)); }

// ---------------------------------------------------------------------------
// K1 (R12): pos-blocked GEMM. R5 counters showed LDS-pipe-bound (8 b128 W
// reads ~96 cyc vs 32 FMA ~64 cyc per 8-k step, VALUBusy 40%). Fix: each
// thread computes 2 ADJACENT positions (2L, 2L+1) so every W element read
// from LDS feeds two FMAs -> FMA-bound (128 vs 96 cyc), and the A-loads for
// the pos-pair become one float2 (dwordx2, coalesced 512B/wave-instr).
// Block = 128 pos x 16 outs (W tile 16x512 = 32KB, staging/bias unchanged);
// grid 13 x 27; mTile 12 covers pos 1536..1663: loads clamped to base 1598
// (never OOB), stores guarded per-pos. Per-acc FMA chains strictly
// sequential ascending k, same A/W values -> bitwise-identical outputs.
// ---------------------------------------------------------------------------
__global__ __launch_bounds__(256) void k_gemm(
    const float* __restrict__ cls_feat, const float* __restrict__ reg_feat,
    const float* __restrict__ w_obj, const float* __restrict__ b_obj,
    const float* __restrict__ w_cls, const float* __restrict__ b_cls,
    const float* __restrict__ w_reg, const float* __restrict__ b_reg,
    float* __restrict__ clsRaw,   // [1600][400]
    float* __restrict__ roRaw)    // [1600][25]: 0..4 obj, 5..24 reg
{
    __shared__ float Ws[16 * KDIM];        // 32 KB
    const int mTile = blockIdx.x;          // 0..12  (128 positions each)
    const int nTile = blockIdx.y;          // 0..26
    const int hw0   = mTile * 128;
    const bool isCls = (nTile < 25);
    const float* feat = isCls ? cls_feat : reg_feat;

    const int lane = threadIdx.x & 63;
    const int og   = threadIdx.x >> 6;     // 0..3 (wave-uniform by construction)

    // This thread's adjacent position pair.
    const int pA = hw0 + 2 * lane;         // even
    const int pB = pA + 1;                 // odd
    const bool vA = (pA < NPOS);
    const bool vB = (pB < NPOS);
    int pbase = pA;
    if (pbase > NPOS - 2) pbase = NPOS - 2;          // clamp: loads always in-bounds

    // float2 pointer: k stride = NPOS floats = NPOS/2 float2s.
    const float2* ap2 = (const float2*)feat + (pbase >> 1);

    // Initial A prefetch (k=0..15) — independent of W staging, issue early.
    float2 A0[8], A1[8];
#pragma unroll
    for (int t = 0; t < 8; t++) A0[t] = ap2[t * (NPOS / 2)];
#pragma unroll
    for (int t = 0; t < 8; t++) A1[t] = ap2[(8 + t) * (NPOS / 2)];

    // ---- stage W tile [16][512] (coalesced float4; 8 iters/thread) ----
    for (int i = threadIdx.x * 4; i < 16 * KDIM; i += 256 * 4) {
        int r = i >> 9, k = i & 511;
        const float* src;
        bool valid = true;
        if (isCls) {
            src = w_cls + (nTile * 16 + r) * KDIM + k;
        } else {
            int o = (nTile - 25) * 16 + r;
            if (o < 5)       src = w_obj + o * KDIM + k;
            else if (o < 25) src = w_reg + (o - 5) * KDIM + k;
            else           { src = w_obj; valid = false; }
        }
        float4 v = valid ? *(const float4*)src : make_float4(0.f, 0.f, 0.f, 0.f);
        *(float4*)&Ws[i] = v;
    }

    // ---- per-thread output metadata (wave-uniform) ----
    float bias[4];
    bool ok[4];
#pragma unroll
    for (int j = 0; j < 4; j++) {
        int r = og * 4 + j;
        if (isCls) {
            bias[j] = b_cls[nTile * 16 + r]; ok[j] = true;
        } else {
            int o = (nTile - 25) * 16 + r;
            if (o < 5)       { bias[j] = b_obj[o];     ok[j] = true; }
            else if (o < 25) { bias[j] = b_reg[o - 5]; ok[j] = true; }
            else             { bias[j] = 0.0f;         ok[j] = false; }
        }
    }

    __syncthreads();   // Ws ready; only barrier in the kernel

    float accA[4] = {0.f, 0.f, 0.f, 0.f};
    float accB[4] = {0.f, 0.f, 0.f, 0.f};
    const float* wsBase = &Ws[(og * 4) * KDIM];

    // Main loop: pairs of 8-k steps; prefetch 16 k ahead. kk = 0..480.
    for (int kk = 0; kk < KDIM - 16; kk += 16) {
        // consume A0 (k = kk..kk+7): each wp[t] feeds both positions
#pragma unroll
        for (int j = 0; j < 4; j++) {
            const float* wp = wsBase + j * KDIM + kk;    // LDS b128 x2, broadcast
            accA[j] += A0[0].x * wp[0]; accA[j] += A0[1].x * wp[1];
            accA[j] += A0[2].x * wp[2]; accA[j] += A0[3].x * wp[3];
            accA[j] += A0[4].x * wp[4]; accA[j] += A0[5].x * wp[5];
            accA[j] += A0[6].x * wp[6]; accA[j] += A0[7].x * wp[7];
            accB[j] += A0[0].y * wp[0]; accB[j] += A0[1].y * wp[1];
            accB[j] += A0[2].y * wp[2]; accB[j] += A0[3].y * wp[3];
            accB[j] += A0[4].y * wp[4]; accB[j] += A0[5].y * wp[5];
            accB[j] += A0[6].y * wp[6]; accB[j] += A0[7].y * wp[7];
        }
#pragma unroll
        for (int t = 0; t < 8; t++) A0[t] = ap2[(kk + 16 + t) * (NPOS / 2)];
        // consume A1 (k = kk+8..kk+15)
#pragma unroll
        for (int j = 0; j < 4; j++) {
            const float* wp = wsBase + j * KDIM + kk + 8;
            accA[j] += A1[0].x * wp[0]; accA[j] += A1[1].x * wp[1];
            accA[j] += A1[2].x * wp[2]; accA[j] += A1[3].x * wp[3];
            accA[j] += A1[4].x * wp[4]; accA[j] += A1[5].x * wp[5];
            accA[j] += A1[6].x * wp[6]; accA[j] += A1[7].x * wp[7];
            accB[j] += A1[0].y * wp[0]; accB[j] += A1[1].y * wp[1];
            accB[j] += A1[2].y * wp[2]; accB[j] += A1[3].y * wp[3];
            accB[j] += A1[4].y * wp[4]; accB[j] += A1[5].y * wp[5];
            accB[j] += A1[6].y * wp[6]; accB[j] += A1[7].y * wp[7];
        }
#pragma unroll
        for (int t = 0; t < 8; t++) A1[t] = ap2[(kk + 24 + t) * (NPOS / 2)];
    }
    // tail: k = 496..511, no prefetch
    {
        const int kk = KDIM - 16;
#pragma unroll
        for (int j = 0; j < 4; j++) {
            const float* wp = wsBase + j * KDIM + kk;
            accA[j] += A0[0].x * wp[0]; accA[j] += A0[1].x * wp[1];
            accA[j] += A0[2].x * wp[2]; accA[j] += A0[3].x * wp[3];
            accA[j] += A0[4].x * wp[4]; accA[j] += A0[5].x * wp[5];
            accA[j] += A0[6].x * wp[6]; accA[j] += A0[7].x * wp[7];
            accB[j] += A0[0].y * wp[0]; accB[j] += A0[1].y * wp[1];
            accB[j] += A0[2].y * wp[2]; accB[j] += A0[3].y * wp[3];
            accB[j] += A0[4].y * wp[4]; accB[j] += A0[5].y * wp[5];
            accB[j] += A0[6].y * wp[6]; accB[j] += A0[7].y * wp[7];
        }
#pragma unroll
        for (int j = 0; j < 4; j++) {
            const float* wp = wsBase + j * KDIM + kk + 8;
            accA[j] += A1[0].x * wp[0]; accA[j] += A1[1].x * wp[1];
            accA[j] += A1[2].x * wp[2]; accA[j] += A1[3].x * wp[3];
            accA[j] += A1[4].x * wp[4]; accA[j] += A1[5].x * wp[5];
            accA[j] += A1[6].x * wp[6]; accA[j] += A1[7].x * wp[7];
            accB[j] += A1[0].y * wp[0]; accB[j] += A1[1].y * wp[1];
            accB[j] += A1[2].y * wp[2]; accB[j] += A1[3].y * wp[3];
            accB[j] += A1[4].y * wp[4]; accB[j] += A1[5].y * wp[5];
            accB[j] += A1[6].y * wp[6]; accB[j] += A1[7].y * wp[7];
        }
    }

    if (isCls) {
        if (vA) {
            float4 rv = make_float4(accA[0] + bias[0], accA[1] + bias[1],
                                    accA[2] + bias[2], accA[3] + bias[3]);
            *(float4*)&clsRaw[pA * 400 + nTile * 16 + og * 4] = rv;
        }
        if (vB) {
            float4 rv = make_float4(accB[0] + bias[0], accB[1] + bias[1],
                                    accB[2] + bias[2], accB[3] + bias[3]);
            *(float4*)&clsRaw[pB * 400 + nTile * 16 + og * 4] = rv;
        }
    } else {
#pragma unroll
        for (int j = 0; j < 4; j++) {
            int o = (nTile - 25) * 16 + og * 4 + j;
            if (ok[j]) {
                if (vA) roRaw[pA * 25 + o] = accA[j] + bias[j];
                if (vB) roRaw[pB * 25 + o] = accB[j] + bias[j];
            }
        }
    }
}

// ---------------------------------------------------------------------------
// K2: per-box scores, argmax label, decode, outputs. BYTE-IDENTICAL to the
// R5/R7/R8/R9-verified kernel.
// ---------------------------------------------------------------------------
__global__ __launch_bounds__(256) void k_box(
    const float* __restrict__ clsRaw, const float* __restrict__ roRaw,
    float* __restrict__ out,          // d_out: [32000 bboxes][8000 score][8000 labels][8000 keep]
    float4* __restrict__ nmsBox, float* __restrict__ nmsArea,
    float2* __restrict__ sl)          // packed (score,label) for k_nms scan
{
    const int n = blockIdx.x * 4 + (threadIdx.x >> 6);   // box index 0..7999
    const int lane = threadIdx.x & 63;
    const int hw = n / 5, a = n % 5;

    const float sobj = sigf(roRaw[hw * 25 + a]);
    const float* cbase = clsRaw + hw * 400 + a * 80;

    const int l4 = (lane < 20) ? lane : 19;     // clamp for safe address
    float4 cs = *(const float4*)(cbase + l4 * 4);

    float s0 = sqrtf(sobj * sigf(cs.x));
    float s1 = sqrtf(sobj * sigf(cs.y));
    float s2 = sqrtf(sobj * sigf(cs.z));
    float s3 = sqrtf(sobj * sigf(cs.w));
    float v = s0; int bi = l4 * 4;
    if (s1 > v) { v = s1; bi = l4 * 4 + 1; }
    if (s2 > v) { v = s2; bi = l4 * 4 + 2; }
    if (s3 > v) { v = s3; bi = l4 * 4 + 3; }
    if (lane >= 20) { v = -1.0f; bi = 0x7FFFFFFF; }  // scores are always > 0

#pragma unroll
    for (int off = 32; off >= 1; off >>= 1) {
        float ov = __shfl_xor(v, off);
        int   oi = __shfl_xor(bi, off);
        if (ov > v || (ov == v && oi < bi)) { v = ov; bi = oi; }
    }

    if (lane == 0) {
        const float* rp = roRaw + hw * 25 + 5 + a * 4;
        float r0 = rp[0], r1 = rp[1], r2 = rp[2], r3 = rp[3];
        float gx = (float)(hw % FMPX), gy = (float)(hw / FMPX);
        float cx = (sigf(r0) + gx) * 32.0f;
        float cy = (sigf(r1) + gy) * 32.0f;
        float wv = expf(r2) * c_aw[a];
        float hv = expf(r3) * c_ah[a];
        float x1 = cx - wv * 0.5f, y1 = cy - hv * 0.5f;
        float x2 = cx + wv * 0.5f, y2 = cy + hv * 0.5f;

        out[n * 4 + 0] = x1; out[n * 4 + 1] = y1;
        out[n * 4 + 2] = x2; out[n * 4 + 3] = y2;
        out[32000 + n] = v;
        out[40000 + n] = (float)bi;
        out[48000 + n] = 0.0f;            // keep init (k_nms sets 1s later)
        sl[n] = make_float2(v, (float)bi);

        // b2: reinterpret x1y1x2y2 as cxcywh (faithful to the reference nms())
        float nx1 = x1 - x2 * 0.5f, ny1 = y1 - y2 * 0.5f;
        float nx2 = x1 + x2 * 0.5f, ny2 = y1 + y2 * 0.5f;
        nmsBox[n]  = make_float4(nx1, ny1, nx2, ny2);
        nmsArea[n] = (nx2 - nx1) * (ny2 - ny1);
    }
}

// ---------------------------------------------------------------------------
// K3: VERBATIM the R9-verified kernel (passed, 50.6 us, keep-set verified).
// The R10 packed-key variant died twice at container level and is shelved.
// Phases: scan+compact (R5-proven); rank-sort by counting; parallel edge-
// matrix build (bit j of row p = iou(p,j) > 0.5, identical IoU expression);
// mask-only serial resolution on wave 0 (ctz-scan, uniform row reads,
// A &= ~row; self-bit retires winner; one LDS wait per KEPT box).
// ---------------------------------------------------------------------------
__global__ __launch_bounds__(256) void k_nms(
    const float2* __restrict__ sl,
    const float4* __restrict__ nmsBox, const float* __restrict__ nmsArea,
    float* __restrict__ keepOut)
{
    const int c = blockIdx.x;

    __shared__ float  ss[CAP];
    __shared__ int    si[CAP];
    __shared__ float4 sb4[CAP];                       // sorted boxes
    __shared__ float  sar[CAP];                       // sorted areas
    __shared__ int    rid[CAP];                       // sorted original ids
    __shared__ unsigned long long erow[4][CAP];       // edge rows, word-major
    __shared__ int    cnt;

    if (threadIdx.x == 0) cnt = 0;
    __syncthreads();

    // ---- phase 1: scan + compact (proven) ----
#pragma unroll 4
    for (int i = threadIdx.x; i < NBOX; i += 256) {
        float2 p = sl[i];
        if (p.x >= 0.3f && (int)p.y == c) {
            int q = atomicAdd(&cnt, 1);          // LDS atomic
            if (q < CAP) { ss[q] = p.x; si[q] = i; }
        }
    }
    __syncthreads();

    int m = cnt;
    if (m > CAP) m = CAP;                        // overflow drop == R5 semantics

    // ---- phase 2: rank-sort by counting + scatter into sorted arrays ----
    {
        const int t = threadIdx.x;
        if (t < m) {
            const float msc = ss[t];
            const int   mid = si[t];
            // issue global gathers early; latency hides under the rank loop
            const float4 b = nmsBox[mid];
            const float  a = nmsArea[mid];
            int rank = 0;
            for (int j = 0; j < m; j++) {        // LDS broadcast reads
                float sj = ss[j]; int ij = si[j];
                if (sj > msc || (sj == msc && ij < mid)) rank++;
            }
            sb4[rank] = b; sar[rank] = a; rid[rank] = mid;
        }
    }
    __syncthreads();

    // ---- phase 2.5: parallel edge-matrix build ----
    {
        const int p = threadIdx.x;
        if (p < m) {
            const float4 pb = sb4[p];
            const float  pa = sar[p];
#pragma unroll
            for (int w = 0; w < 4; w++) {        // compile-time w (rule #20)
                unsigned long long ew = 0ull;
                const int j0 = w * 64;
                const int j1 = (m < j0 + 64) ? m : (j0 + 64);
                for (int j = j0; j < j1; j++) {
                    float4 bj = sb4[j];          // broadcast b128
                    float  aj = sar[j];
                    float xx1 = fmaxf(pb.x, bj.x);
                    float yy1 = fmaxf(pb.y, bj.y);
                    float xx2 = fminf(pb.z, bj.z);
                    float yy2 = fminf(pb.w, bj.w);
                    float inter = fmaxf(1e-10f, xx2 - xx1) * fmaxf(1e-10f, yy2 - yy1);
                    float iou = inter / ((pa + aj - inter) + 1e-14f);
                    if (iou > 0.5f) ew |= (1ull << (j & 63));
                }
                erow[w][p] = ew;
            }
        }
    }
    __syncthreads();

    // ---- phase 3: mask-only serial resolution, wave 0 ----
    if (threadIdx.x >= 64) return;
    const int lane = threadIdx.x;

    unsigned long long A[4];
#pragma unroll
    for (int w = 0; w < 4; w++) {
        int lo = w * 64;
        A[w] = (m >= lo + 64) ? ~0ull
             : (m > lo ? ((1ull << (m - lo)) - 1ull) : 0ull);
    }

    for (int guard = 0; guard < m; guard++) {
        int k = -1;
#pragma unroll
        for (int w = 0; w < 4; w++)
            if (k < 0 && A[w] != 0ull) k = w * 64 + (int)__builtin_ctzll(A[w]);
        if (k < 0) break;

        // the only memory wait in the loop: row + id, uniform broadcast reads
        unsigned long long r0 = erow[0][k];
        unsigned long long r1 = erow[1][k];
        unsigned long long r2 = erow[2][k];
        unsigned long long r3 = erow[3][k];
        int kid = rid[k];
        if (lane == 0) keepOut[kid] = 1.0f;

#pragma unroll
        for (int w = 0; w < 4; w++)              // static-index self-clear
            if ((k >> 6) == w) A[w] &= ~(1ull << (k & 63));
        A[0] &= ~r0; A[1] &= ~r1; A[2] &= ~r2; A[3] &= ~r3;
    }
}

// ---------------------------------------------------------------------------
extern "C" void kernel_launch(void* const* d_in, const int* in_sizes, int n_in,
                              void* d_out, int out_size, void* d_ws, size_t ws_size,
                              hipStream_t stream) {
    const float* cls_feat = (const float*)d_in[0];
    const float* reg_feat = (const float*)d_in[1];
    const float* w_obj    = (const float*)d_in[2];
    const float* b_obj    = (const float*)d_in[3];
    const float* w_cls    = (const float*)d_in[4];
    const float* b_cls    = (const float*)d_in[5];
    const float* w_reg    = (const float*)d_in[6];
    const float* b_reg    = (const float*)d_in[7];

    float* out = (float*)d_out;
    float* ws  = (float*)d_ws;

    // workspace layout (floats) — IDENTICAL to the R5-proven layout, 2.944 MB
    float*  clsRaw    = ws;                       // 640000
    float*  roRaw     = ws + 640000;              // 40000
    float4* nmsBox    = (float4*)(ws + 680000);   // 32000 floats (16B-aligned offset)
    float*  nmsArea   = ws + 712000;              // 8000
    float2* sl        = (float2*)(ws + 720000);   // 16000 floats (8B-aligned)
    // total 736000 floats

    k_gemm<<<dim3(13, 27), 256, 0, stream>>>(cls_feat, reg_feat,
                                             w_obj, b_obj, w_cls, b_cls, w_reg, b_reg,
                                             clsRaw, roRaw);
    k_box<<<NBOX / 4, 256, 0, stream>>>(clsRaw, roRaw, out, nmsBox, nmsArea, sl);
    k_nms<<<NCLS, 256, 0, stream>>>(sl, nmsBox, nmsArea, out + 48000);
}

// Round 9
// 160.560 us; speedup vs baseline: 1.0107x; 1.0107x over previous
//
#include <hip/hip_runtime.h>
#include <math.h>

#define FMPX 40
#define NPOS 1600          // 40*40
#define NCLS 80
#define NBOX 8000
#define KDIM 512
#define CAP  256           // per-class candidate capacity (expected ~100-130/class)

// anchor (w,h) pairs
__constant__ float c_aw[5] = {17.f, 55.f, 92.f, 202.f, 289.f};
__constant__ float c_ah[5] = {25.f, 75.f, 206.f, 21.f, 311.f};

__device__ __forceinline__ float sigf(float x) { return 1.0f / (1.0f + expf(-x)); }

// ---------------------------------------------------------------------------
// K1: the three 1x1-conv GEMMs. BYTE-IDENTICAL to the R5/R7/R8/R9-verified
// kernel (42.4 us, VALUBusy 40%). R12 lesson: 2-pos blocking regressed +5 us
// — grid 675->351 blocks dropped occupancy to ~1 wave/SIMD, exposing the
// A-prefetch vmcnt waits that TLP had hidden; per-thread arithmetic models
// must include wave count. R3: both A+W in LDS -> LDS-pipe-bound. R4:
// per-step s_load W worse. R5: A from GLOBAL (L2-resident), 2x8-k register
// pipeline; W staged once in LDS; no barriers in K-loop. FMA order strictly
// sequential ascending k — bitwise-identical (absmax 2.0 stable).
// ---------------------------------------------------------------------------
__global__ __launch_bounds__(256) void k_gemm(
    const float* __restrict__ cls_feat, const float* __restrict__ reg_feat,
    const float* __restrict__ w_obj, const float* __restrict__ b_obj,
    const float* __restrict__ w_cls, const float* __restrict__ b_cls,
    const float* __restrict__ w_reg, const float* __restrict__ b_reg,
    float* __restrict__ clsRaw,   // [1600][400]
    float* __restrict__ roRaw)    // [1600][25]: 0..4 obj, 5..24 reg
{
    __shared__ float Ws[16 * KDIM];        // 32 KB
    const int mTile = blockIdx.x;          // 0..24
    const int nTile = blockIdx.y;          // 0..26
    const int hw0   = mTile * 64;
    const bool isCls = (nTile < 25);
    const float* feat = isCls ? cls_feat : reg_feat;

    const int pos = threadIdx.x & 63;
    const int og  = threadIdx.x >> 6;      // 0..3 (wave-uniform by construction)

    const float* ap = feat + hw0 + pos;

    float A0[8], A1[8];
#pragma unroll
    for (int t = 0; t < 8; t++) A0[t] = ap[t * NPOS];
#pragma unroll
    for (int t = 0; t < 8; t++) A1[t] = ap[(8 + t) * NPOS];

    for (int i = threadIdx.x * 4; i < 16 * KDIM; i += 256 * 4) {
        int r = i >> 9, k = i & 511;
        const float* src;
        bool valid = true;
        if (isCls) {
            src = w_cls + (nTile * 16 + r) * KDIM + k;
        } else {
            int o = (nTile - 25) * 16 + r;
            if (o < 5)       src = w_obj + o * KDIM + k;
            else if (o < 25) src = w_reg + (o - 5) * KDIM + k;
            else           { src = w_obj; valid = false; }
        }
        float4 v = valid ? *(const float4*)src : make_float4(0.f, 0.f, 0.f, 0.f);
        *(float4*)&Ws[i] = v;
    }

    float bias[4];
    bool ok[4];
#pragma unroll
    for (int j = 0; j < 4; j++) {
        int r = og * 4 + j;
        if (isCls) {
            bias[j] = b_cls[nTile * 16 + r]; ok[j] = true;
        } else {
            int o = (nTile - 25) * 16 + r;
            if (o < 5)       { bias[j] = b_obj[o];     ok[j] = true; }
            else if (o < 25) { bias[j] = b_reg[o - 5]; ok[j] = true; }
            else             { bias[j] = 0.0f;         ok[j] = false; }
        }
    }

    __syncthreads();   // Ws ready; only barrier in the kernel

    float acc[4] = {0.f, 0.f, 0.f, 0.f};
    const float* wsBase = &Ws[(og * 4) * KDIM];

    for (int kk = 0; kk < KDIM - 16; kk += 16) {
#pragma unroll
        for (int j = 0; j < 4; j++) {
            const float* wp = wsBase + j * KDIM + kk;
            acc[j] += A0[0] * wp[0]; acc[j] += A0[1] * wp[1];
            acc[j] += A0[2] * wp[2]; acc[j] += A0[3] * wp[3];
            acc[j] += A0[4] * wp[4]; acc[j] += A0[5] * wp[5];
            acc[j] += A0[6] * wp[6]; acc[j] += A0[7] * wp[7];
        }
#pragma unroll
        for (int t = 0; t < 8; t++) A0[t] = ap[(kk + 16 + t) * NPOS];
#pragma unroll
        for (int j = 0; j < 4; j++) {
            const float* wp = wsBase + j * KDIM + kk + 8;
            acc[j] += A1[0] * wp[0]; acc[j] += A1[1] * wp[1];
            acc[j] += A1[2] * wp[2]; acc[j] += A1[3] * wp[3];
            acc[j] += A1[4] * wp[4]; acc[j] += A1[5] * wp[5];
            acc[j] += A1[6] * wp[6]; acc[j] += A1[7] * wp[7];
        }
#pragma unroll
        for (int t = 0; t < 8; t++) A1[t] = ap[(kk + 24 + t) * NPOS];
    }
    {
        const int kk = KDIM - 16;
#pragma unroll
        for (int j = 0; j < 4; j++) {
            const float* wp = wsBase + j * KDIM + kk;
            acc[j] += A0[0] * wp[0]; acc[j] += A0[1] * wp[1];
            acc[j] += A0[2] * wp[2]; acc[j] += A0[3] * wp[3];
            acc[j] += A0[4] * wp[4]; acc[j] += A0[5] * wp[5];
            acc[j] += A0[6] * wp[6]; acc[j] += A0[7] * wp[7];
        }
#pragma unroll
        for (int j = 0; j < 4; j++) {
            const float* wp = wsBase + j * KDIM + kk + 8;
            acc[j] += A1[0] * wp[0]; acc[j] += A1[1] * wp[1];
            acc[j] += A1[2] * wp[2]; acc[j] += A1[3] * wp[3];
            acc[j] += A1[4] * wp[4]; acc[j] += A1[5] * wp[5];
            acc[j] += A1[6] * wp[6]; acc[j] += A1[7] * wp[7];
        }
    }

    const int hw = hw0 + pos;
    if (isCls) {
        float4 rv = make_float4(acc[0] + bias[0], acc[1] + bias[1],
                                acc[2] + bias[2], acc[3] + bias[3]);
        *(float4*)&clsRaw[hw * 400 + nTile * 16 + og * 4] = rv;
    } else {
#pragma unroll
        for (int j = 0; j < 4; j++) {
            int o = (nTile - 25) * 16 + og * 4 + j;
            if (ok[j]) roRaw[hw * 25 + o] = acc[j] + bias[j];
        }
    }
}

// ---------------------------------------------------------------------------
// K2: per-box scores, argmax label, decode, outputs. BYTE-IDENTICAL to the
// R5/R7/R8/R9-verified kernel.
// ---------------------------------------------------------------------------
__global__ __launch_bounds__(256) void k_box(
    const float* __restrict__ clsRaw, const float* __restrict__ roRaw,
    float* __restrict__ out,          // d_out: [32000 bboxes][8000 score][8000 labels][8000 keep]
    float4* __restrict__ nmsBox, float* __restrict__ nmsArea,
    float2* __restrict__ sl)          // packed (score,label) for k_nms scan
{
    const int n = blockIdx.x * 4 + (threadIdx.x >> 6);   // box index 0..7999
    const int lane = threadIdx.x & 63;
    const int hw = n / 5, a = n % 5;

    const float sobj = sigf(roRaw[hw * 25 + a]);
    const float* cbase = clsRaw + hw * 400 + a * 80;

    const int l4 = (lane < 20) ? lane : 19;     // clamp for safe address
    float4 cs = *(const float4*)(cbase + l4 * 4);

    float s0 = sqrtf(sobj * sigf(cs.x));
    float s1 = sqrtf(sobj * sigf(cs.y));
    float s2 = sqrtf(sobj * sigf(cs.z));
    float s3 = sqrtf(sobj * sigf(cs.w));
    float v = s0; int bi = l4 * 4;
    if (s1 > v) { v = s1; bi = l4 * 4 + 1; }
    if (s2 > v) { v = s2; bi = l4 * 4 + 2; }
    if (s3 > v) { v = s3; bi = l4 * 4 + 3; }
    if (lane >= 20) { v = -1.0f; bi = 0x7FFFFFFF; }  // scores are always > 0

#pragma unroll
    for (int off = 32; off >= 1; off >>= 1) {
        float ov = __shfl_xor(v, off);
        int   oi = __shfl_xor(bi, off);
        if (ov > v || (ov == v && oi < bi)) { v = ov; bi = oi; }
    }

    if (lane == 0) {
        const float* rp = roRaw + hw * 25 + 5 + a * 4;
        float r0 = rp[0], r1 = rp[1], r2 = rp[2], r3 = rp[3];
        float gx = (float)(hw % FMPX), gy = (float)(hw / FMPX);
        float cx = (sigf(r0) + gx) * 32.0f;
        float cy = (sigf(r1) + gy) * 32.0f;
        float wv = expf(r2) * c_aw[a];
        float hv = expf(r3) * c_ah[a];
        float x1 = cx - wv * 0.5f, y1 = cy - hv * 0.5f;
        float x2 = cx + wv * 0.5f, y2 = cy + hv * 0.5f;

        out[n * 4 + 0] = x1; out[n * 4 + 1] = y1;
        out[n * 4 + 2] = x2; out[n * 4 + 3] = y2;
        out[32000 + n] = v;
        out[40000 + n] = (float)bi;
        out[48000 + n] = 0.0f;            // keep init (k_nms sets 1s later)
        sl[n] = make_float2(v, (float)bi);

        // b2: reinterpret x1y1x2y2 as cxcywh (faithful to the reference nms())
        float nx1 = x1 - x2 * 0.5f, ny1 = y1 - y2 * 0.5f;
        float nx2 = x1 + x2 * 0.5f, ny2 = y1 + y2 * 0.5f;
        nmsBox[n]  = make_float4(nx1, ny1, nx2, ny2);
        nmsArea[n] = (nx2 - nx1) * (ny2 - ny1);
    }
}

// ---------------------------------------------------------------------------
// K3 (R13): R9-verified body (passed, 50.6/50.1 us, keep-set verified) with
// ONLY latency-pipelining deltas — no shelved constructs (no global bucket
// atomics, no packed-u64 keys; those sources died at container level):
//   * rank loop gets #pragma unroll 4 (same pragma already proven on the
//     scan loop): 8 independent LDS loads batched per waitcnt instead of 2.
//   * edge build spread over (p,w) pairs — 4m work items across all 256
//     threads (was m rows on m threads) — plus unroll 4 on the inner j-loop.
//     Same IoU expression, same sar[] reads, same erow[] writes.
//   * scan / rank semantics / resolve: verbatim R9.
// No FP op added/removed/reordered -> identical keep set, absmax 2.0.
// ---------------------------------------------------------------------------
__global__ __launch_bounds__(256) void k_nms(
    const float2* __restrict__ sl,
    const float4* __restrict__ nmsBox, const float* __restrict__ nmsArea,
    float* __restrict__ keepOut)
{
    const int c = blockIdx.x;

    __shared__ float  ss[CAP];
    __shared__ int    si[CAP];
    __shared__ float4 sb4[CAP];                       // sorted boxes
    __shared__ float  sar[CAP];                       // sorted areas
    __shared__ int    rid[CAP];                       // sorted original ids
    __shared__ unsigned long long erow[4][CAP];       // edge rows, word-major
    __shared__ int    cnt;

    if (threadIdx.x == 0) cnt = 0;
    __syncthreads();

    // ---- phase 1: scan + compact (proven) ----
#pragma unroll 4
    for (int i = threadIdx.x; i < NBOX; i += 256) {
        float2 p = sl[i];
        if (p.x >= 0.3f && (int)p.y == c) {
            int q = atomicAdd(&cnt, 1);          // LDS atomic
            if (q < CAP) { ss[q] = p.x; si[q] = i; }
        }
    }
    __syncthreads();

    int m = cnt;
    if (m > CAP) m = CAP;                        // overflow drop == R5 semantics

    // ---- phase 2: rank-sort by counting + scatter into sorted arrays ----
    {
        const int t = threadIdx.x;
        if (t < m) {
            const float msc = ss[t];
            const int   mid = si[t];
            // issue global gathers early; latency hides under the rank loop
            const float4 b = nmsBox[mid];
            const float  a = nmsArea[mid];
            int rank = 0;
#pragma unroll 4
            for (int j = 0; j < m; j++) {        // LDS broadcast reads
                float sj = ss[j]; int ij = si[j];
                if (sj > msc || (sj == msc && ij < mid)) rank++;
            }
            sb4[rank] = b; sar[rank] = a; rid[rank] = mid;
        }
    }
    __syncthreads();

    // ---- phase 2.5: parallel edge build over (p,w) pairs, all 256 thr ----
    {
        const int mw = m << 2;
        for (int pw = threadIdx.x; pw < mw; pw += 256) {
            const int p = pw >> 2, w = pw & 3;
            const float4 pb = sb4[p];
            const float  pa = sar[p];
            unsigned long long ew = 0ull;
            const int j0 = w << 6;
            const int j1 = (m < j0 + 64) ? m : (j0 + 64);
#pragma unroll 4
            for (int j = j0; j < j1; j++) {
                float4 bj = sb4[j];              // broadcast b128
                float  aj = sar[j];
                float xx1 = fmaxf(pb.x, bj.x);
                float yy1 = fmaxf(pb.y, bj.y);
                float xx2 = fminf(pb.z, bj.z);
                float yy2 = fminf(pb.w, bj.w);
                float inter = fmaxf(1e-10f, xx2 - xx1) * fmaxf(1e-10f, yy2 - yy1);
                float iou = inter / ((pa + aj - inter) + 1e-14f);
                if (iou > 0.5f) ew |= (1ull << (j & 63));
            }
            erow[w][p] = ew;                     // self-bit of p always set
        }
    }
    __syncthreads();

    // ---- phase 3: mask-only serial resolution, wave 0 (verbatim R9) ----
    if (threadIdx.x >= 64) return;
    const int lane = threadIdx.x;

    unsigned long long A[4];
#pragma unroll
    for (int w = 0; w < 4; w++) {
        int lo = w * 64;
        A[w] = (m >= lo + 64) ? ~0ull
             : (m > lo ? ((1ull << (m - lo)) - 1ull) : 0ull);
    }

    for (int guard = 0; guard < m; guard++) {
        int k = -1;
#pragma unroll
        for (int w = 0; w < 4; w++)
            if (k < 0 && A[w] != 0ull) k = w * 64 + (int)__builtin_ctzll(A[w]);
        if (k < 0) break;

        // the only memory wait in the loop: row + id, uniform broadcast reads
        unsigned long long r0 = erow[0][k];
        unsigned long long r1 = erow[1][k];
        unsigned long long r2 = erow[2][k];
        unsigned long long r3 = erow[3][k];
        int kid = rid[k];
        if (lane == 0) keepOut[kid] = 1.0f;

#pragma unroll
        for (int w = 0; w < 4; w++)              // static-index self-clear
            if ((k >> 6) == w) A[w] &= ~(1ull << (k & 63));
        A[0] &= ~r0; A[1] &= ~r1; A[2] &= ~r2; A[3] &= ~r3;
    }
}

// ---------------------------------------------------------------------------
extern "C" void kernel_launch(void* const* d_in, const int* in_sizes, int n_in,
                              void* d_out, int out_size, void* d_ws, size_t ws_size,
                              hipStream_t stream) {
    const float* cls_feat = (const float*)d_in[0];
    const float* reg_feat = (const float*)d_in[1];
    const float* w_obj    = (const float*)d_in[2];
    const float* b_obj    = (const float*)d_in[3];
    const float* w_cls    = (const float*)d_in[4];
    const float* b_cls    = (const float*)d_in[5];
    const float* w_reg    = (const float*)d_in[6];
    const float* b_reg    = (const float*)d_in[7];

    float* out = (float*)d_out;
    float* ws  = (float*)d_ws;

    // workspace layout (floats) — IDENTICAL to the R5-proven layout, 2.944 MB
    float*  clsRaw    = ws;                       // 640000
    float*  roRaw     = ws + 640000;              // 40000
    float4* nmsBox    = (float4*)(ws + 680000);   // 32000 floats (16B-aligned offset)
    float*  nmsArea   = ws + 712000;              // 8000
    float2* sl        = (float2*)(ws + 720000);   // 16000 floats (8B-aligned)
    // total 736000 floats

    k_gemm<<<dim3(25, 27), 256, 0, stream>>>(cls_feat, reg_feat,
                                             w_obj, b_obj, w_cls, b_cls, w_reg, b_reg,
                                             clsRaw, roRaw);
    k_box<<<NBOX / 4, 256, 0, stream>>>(clsRaw, roRaw, out, nmsBox, nmsArea, sl);
    k_nms<<<NCLS, 256, 0, stream>>>(sl, nmsBox, nmsArea, out + 48000);
}